// Round 12
// baseline (155.761 us; speedup 1.0000x reference)
//
#include <hip/hip_runtime.h>
#include <math.h>

#define N_   4
#define LQ_  5440
#define MQ_  (N_*LQ_)   // 21760 rows; /8 = 2720 blocks; /128 = 170 tiles

typedef _Float16 f16;
typedef __attribute__((ext_vector_type(2))) _Float16 f16x2;
typedef __attribute__((ext_vector_type(8))) _Float16 f16x8;
typedef __attribute__((ext_vector_type(4))) float     f32x4;

__device__ __forceinline__ unsigned short f2h(float f) {
  union { f16 h; unsigned short u; } v; v.h = (f16)f; return v.u;
}
__device__ __forceinline__ float h2f(unsigned u) {   // low 16 bits
  union { unsigned short u; f16 h; } v; v.u = (unsigned short)u; return (float)v.h;
}
__device__ __forceinline__ f16x2 u2h2(unsigned u) {
  union { unsigned u; f16x2 h; } v; v.u = u; return v.h;
}

#define GLD16(gp, lp) __builtin_amdgcn_global_load_lds( \
    (const __attribute__((address_space(1))) void*)(gp), \
    (__attribute__((address_space(3))) void*)(lp), 16, 0, 0)

// -------- stage-1 GEMM, col-tile loop INSIDE the block --------------------------
// grid (170, src, stream). Both A AND W are reg-staged from fp32 with in-register
// f16 cvt + swizzled ds_write (W panels are L2-resident; no prep dependency).
__global__ __launch_bounds__(256)
void gemm_stage1(const float* __restrict__ q0, const float* __restrict__ q1,
                 const float* __restrict__ f0, const float* __restrict__ f1,
                 const float* __restrict__ Wval32, const float* __restrict__ Woff32,
                 const float* __restrict__ Wattn32,
                 const float* __restrict__ b_val, const float* __restrict__ b_off,
                 const float* __restrict__ b_attn,
                 unsigned short* __restrict__ valb, unsigned short* __restrict__ oab) {
  __shared__ __align__(16) unsigned short As[128 * 64];
  __shared__ __align__(16) unsigned short Ws[128 * 64];
  const int src = blockIdx.y, z = blockIdx.z;
  const size_t SZ = (size_t)MQ_ * 256;
  const float* A; unsigned short* C; int NC, NT;
  if (src == 0) { A = z ? f1 : f0; C = valb + z * SZ;               NC = 256; NT = 2; }
  else          { A = z ? q1 : q0; C = oab + (size_t)z * MQ_ * 384; NC = 384; NT = 3; }

  const int t    = threadIdx.x;
  const int lane = t & 63;
  const int wv   = t >> 6;
  const int wr   = wv >> 1, wc = wv & 1;
  const int row0 = blockIdx.x * 128;
  const int srow = t >> 3, schunk = t & 7;

  for (int ct = 0; ct < NT; ++ct) {
    const int col0 = ct * 128;
    // per-(src,ct) weight source + bias (bias pointer pre-offset to this col-tile)
    const float* Wsrc; const float* bias; int wrow0;
    if (src == 0)      { Wsrc = Wval32;  bias = b_val  + col0; wrow0 = col0; }
    else if (ct < 2)   { Wsrc = Woff32;  bias = b_off  + col0; wrow0 = col0; }
    else               { Wsrc = Wattn32; bias = b_attn;        wrow0 = 0;    }

    f32x4 acc[4][4] = {};

    for (int k0 = 0; k0 < 256; k0 += 64) {
      __syncthreads();
      #pragma unroll
      for (int i = 0; i < 4; ++i) {                // W: fp32 reg-stage + cvt (L2-hot)
        const int row = i * 32 + srow;
        const float* wp = Wsrc + (size_t)(wrow0 + row) * 256 + k0 + schunk * 8;
        const float4 w0 = *reinterpret_cast<const float4*>(wp);
        const float4 w1 = *reinterpret_cast<const float4*>(wp + 4);
        f16x8 hw;
        hw[0] = (f16)w0.x; hw[1] = (f16)w0.y; hw[2] = (f16)w0.z; hw[3] = (f16)w0.w;
        hw[4] = (f16)w1.x; hw[5] = (f16)w1.y; hw[6] = (f16)w1.z; hw[7] = (f16)w1.w;
        const int ch = schunk ^ (row & 7);
        *reinterpret_cast<f16x8*>(&Ws[row * 64 + ch * 8]) = hw;
      }
      #pragma unroll
      for (int i = 0; i < 4; ++i) {                // A: fp32 reg-stage + cvt (L2-hot on ct>0)
        const int row = i * 32 + srow;
        const float* srcp = A + (size_t)(row0 + row) * 256 + k0 + schunk * 8;
        const float4 a0 = *reinterpret_cast<const float4*>(srcp);
        const float4 a1 = *reinterpret_cast<const float4*>(srcp + 4);
        f16x8 hv;
        hv[0] = (f16)a0.x; hv[1] = (f16)a0.y; hv[2] = (f16)a0.z; hv[3] = (f16)a0.w;
        hv[4] = (f16)a1.x; hv[5] = (f16)a1.y; hv[6] = (f16)a1.z; hv[7] = (f16)a1.w;
        const int ch = schunk ^ (row & 7);
        *reinterpret_cast<f16x8*>(&As[row * 64 + ch * 8]) = hv;
      }
      __syncthreads();

      f16x8 af[4][2], bfr[4][2];
      #pragma unroll
      for (int f = 0; f < 4; ++f)
        #pragma unroll
        for (int kk = 0; kk < 2; ++kk) {
          const int ra = wr * 64 + f * 16 + (lane & 15);
          const int ca = (kk * 4 + (lane >> 4)) ^ (ra & 7);
          af[f][kk] = *(const f16x8*)&As[ra * 64 + ca * 8];
          const int rb = wc * 64 + f * 16 + (lane & 15);
          const int cb = (kk * 4 + (lane >> 4)) ^ (rb & 7);
          bfr[f][kk] = *(const f16x8*)&Ws[rb * 64 + cb * 8];
        }
      #pragma unroll
      for (int kk = 0; kk < 2; ++kk)
        #pragma unroll
        for (int fm = 0; fm < 4; ++fm)
          #pragma unroll
          for (int fn = 0; fn < 4; ++fn)
            acc[fm][fn] = __builtin_amdgcn_mfma_f32_16x16x32_f16(
                af[fm][kk], bfr[fn][kk], acc[fm][fn], 0, 0, 0);
    }

    #pragma unroll
    for (int fm = 0; fm < 4; ++fm) {
      const int m = row0 + wr * 64 + fm * 16 + (lane >> 4) * 4;
      #pragma unroll
      for (int fn = 0; fn < 4; ++fn) {
        const int cl = wc * 64 + fn * 16 + (lane & 15);
        const float bv = bias[cl];
        #pragma unroll
        for (int r = 0; r < 4; ++r)
          C[(size_t)(m + r) * NC + col0 + cl] = f2h(acc[fm][fn][r] + bv);
      }
    }
  }
}

// -------- final GEMM: out = acc(MQ,512 f16) @ Wfin^T + bfin, fp32 out ----------
// 64x128 tile (680 blocks for tail balance), K=512. 4 waves = 4 col groups.
__global__ __launch_bounds__(256)
void gemm_final(const unsigned short* __restrict__ A,
                const unsigned short* __restrict__ W,
                const float* __restrict__ bias, float* __restrict__ out) {
  __shared__ __align__(16) unsigned short As[64 * 64];    //  8 KB
  __shared__ __align__(16) unsigned short Ws[128 * 64];   // 16 KB
  const int t    = threadIdx.x;
  const int lane = t & 63;
  const int wv   = t >> 6;                 // column group 0..3 (32 cols each)
  const int row0 = blockIdx.x * 64, col0 = blockIdx.y * 128;
  const int srow = t >> 3, schunk = t & 7;
  const int wbase = wv * 512;

  f32x4 acc[4][2] = {};

  for (int k0 = 0; k0 < 512; k0 += 64) {
    __syncthreads();
    #pragma unroll
    for (int i = 0; i < 2; ++i) {          // A: 64 rows, 2 issues
      const int row = i * 32 + srow;
      const int ch  = schunk ^ (row & 7);
      GLD16(A + (size_t)(row0 + row) * 512 + k0 + ch * 8, &As[i * 2048 + wbase]);
    }
    #pragma unroll
    for (int i = 0; i < 4; ++i) {          // W: 128 rows, 4 issues
      const int row = i * 32 + srow;
      const int ch  = schunk ^ (row & 7);
      GLD16(W + (size_t)(col0 + row) * 512 + k0 + ch * 8, &Ws[i * 2048 + wbase]);
    }
    __syncthreads();

    f16x8 af[4][2], bfr[2][2];
    #pragma unroll
    for (int kk = 0; kk < 2; ++kk) {
      #pragma unroll
      for (int f = 0; f < 4; ++f) {
        const int ra = f * 16 + (lane & 15);
        const int ca = (kk * 4 + (lane >> 4)) ^ (ra & 7);
        af[f][kk] = *(const f16x8*)&As[ra * 64 + ca * 8];
      }
      #pragma unroll
      for (int fn = 0; fn < 2; ++fn) {
        const int rb = wv * 32 + fn * 16 + (lane & 15);
        const int cb = (kk * 4 + (lane >> 4)) ^ (rb & 7);
        bfr[fn][kk] = *(const f16x8*)&Ws[rb * 64 + cb * 8];
      }
    }
    #pragma unroll
    for (int kk = 0; kk < 2; ++kk)
      #pragma unroll
      for (int fm = 0; fm < 4; ++fm)
        #pragma unroll
        for (int fn = 0; fn < 2; ++fn)
          acc[fm][fn] = __builtin_amdgcn_mfma_f32_16x16x32_f16(
              af[fm][kk], bfr[fn][kk], acc[fm][fn], 0, 0, 0);
  }

  #pragma unroll
  for (int fm = 0; fm < 4; ++fm) {
    const int m = row0 + fm * 16 + (lane >> 4) * 4;
    #pragma unroll
    for (int fn = 0; fn < 2; ++fn) {
      const int c = col0 + wv * 32 + fn * 16 + (lane & 15);
      const float bv = bias[c];
      #pragma unroll
      for (int r = 0; r < 4; ++r)
        out[(size_t)(m + r) * 256 + c] = acc[fm][fn][r] + bv;
    }
  }
}

// ------------------------- deformable sampling + fused prep tail ---------------
// grid 5440+513 x 256. Blocks <5440: R8's proven sampler (XCD-local slabs,
// 16 KB LDS records, 16-wide gather bursts). Blocks >=5440: prep tail — Wfinh
// (512 blocks: Wfin[j][s*256+k] = sum_i W_agg[j,s*256+i]*W_out[i,k]) + bfin (1).
// Wfinh/bfin are consumed only by the NEXT dispatch (gemm_final) — safe.
__global__ __launch_bounds__(256, 4)
void deform_sample(const unsigned short* __restrict__ vals,  // (2,N,LQ,256) f16
                   const unsigned short* __restrict__ oa,    // (2,MQ,384) f16
                   const float* __restrict__ refp,           // (N,LQ,4,2) f32
                   unsigned short* __restrict__ acc_out,     // (MQ,512) f16
                   const float* __restrict__ W_agg, const float* __restrict__ W_out,
                   const float* __restrict__ b_agg, const float* __restrict__ b_out,
                   unsigned short* __restrict__ Wfinh, float* __restrict__ bfin) {
  __shared__ uint4 lds_rec[8][16][8];   // 16 KB: {idx01, idx23, w01, w23}
  const int bid = blockIdx.x;
  const int t   = threadIdx.x;

  if (bid >= 5440) {                     // ---- prep tail ----
    const int pb = bid - 5440;           // 0..512
    float* wrow = (float*)lds_rec;
    if (pb < 512) {
      const int j = pb & 255, s2 = pb >> 8;
      wrow[t] = W_agg[(size_t)j * 512 + s2 * 256 + t];
      __syncthreads();
      float a = 0.f;
      for (int i = 0; i < 256; ++i)
        a = fmaf(wrow[i], W_out[(size_t)i * 256 + t], a);
      Wfinh[(size_t)j * 512 + s2 * 256 + t] = f2h(a);
    } else {
      float s2 = b_agg[t];
      for (int i = 0; i < 256; ++i)
        s2 = fmaf(W_agg[(size_t)t * 512 + i] + W_agg[(size_t)t * 512 + 256 + i],
                  b_out[i], s2);
      bfin[t] = s2;
    }
    return;
  }

  const int sn  = bid & 7;                // -> XCD k holds slab k
  const int s   = sn >> 2, n = sn & 3;
  const int qb  = bid >> 3;               // 0..679 within (s,n)
  const int q   = t >> 5, tq = t & 31;
  const int row = n * LQ_ + qb * 8 + q;
  const int h   = tq >> 2;

  const unsigned short* oar = oa + ((size_t)s * MQ_ + row) * 384;
  {
    const int   l  = tq & 3;
    const int   Wn = 64 >> l;
    const float Wf = (float)Wn;
    const int   lb = (int)(((0xAD200u >> (5 * l)) & 31u) << 8);  // {0,4096,5120,5376}
    const uint4 ov = *reinterpret_cast<const uint4*>(oar + (size_t)tq * 8);
    const uint2 lv = *reinterpret_cast<const uint2*>(oar + 256 + (size_t)tq * 4);
    const float2 rxy = *reinterpret_cast<const float2*>(refp + (size_t)row * 8 + l * 2);
    float lg[4] = { h2f(lv.x), h2f(lv.x >> 16), h2f(lv.y), h2f(lv.y >> 16) };
    float mx = fmaxf(fmaxf(lg[0], lg[1]), fmaxf(lg[2], lg[3]));
    mx = fmaxf(mx, __shfl_xor(mx, 1));
    mx = fmaxf(mx, __shfl_xor(mx, 2));
    float e[4], se;
    #pragma unroll
    for (int k = 0; k < 4; ++k) e[k] = __expf(lg[k] - mx);
    se = (e[0] + e[1]) + (e[2] + e[3]);
    se += __shfl_xor(se, 1);
    se += __shfl_xor(se, 2);
    const float inv = 1.f / se;
    const unsigned od[4] = { ov.x, ov.y, ov.z, ov.w };
    #pragma unroll
    for (int k = 0; k < 4; ++k) {
      const float ox = h2f(od[k]), oy = h2f(od[k] >> 16);
      const float x = fmaf(rxy.x, Wf, ox) - 0.5f;
      const float y = fmaf(rxy.y, Wf, oy) - 0.5f;
      const float x0f = floorf(x), y0f = floorf(y);
      const int   x0 = (int)x0f,   y0 = (int)y0f;
      const float lx = x - x0f,    ly = y - y0f;
      const float aw = e[k] * inv;
      const int   xs[2] = {x0, x0 + 1}, ys[2] = {y0, y0 + 1};
      const float wx[2] = {1.f - lx, lx}, wy[2] = {1.f - ly, ly};
      unsigned ia[4]; unsigned short wa[4];
      #pragma unroll
      for (int cy = 0; cy < 2; ++cy)
        #pragma unroll
        for (int cx = 0; cx < 2; ++cx) {
          const int xi = xs[cx], yi = ys[cy];
          const bool v = (xi >= 0) && (xi < Wn) && (yi >= 0) && (yi < Wn);
          const int xc = min(max(xi, 0), Wn - 1), yc = min(max(yi, 0), Wn - 1);
          ia[cy * 2 + cx] = (unsigned)(lb + yc * Wn + xc);       // 16-bit row idx
          wa[cy * 2 + cx] = f2h(v ? wx[cx] * wy[cy] * aw : 0.f);
        }
      const int jj = l * 4 + k;
      uint4 rec;
      rec.x = ia[0] | (ia[1] << 16);
      rec.y = ia[2] | (ia[3] << 16);
      rec.z = (unsigned)wa[0] | ((unsigned)wa[1] << 16);
      rec.w = (unsigned)wa[2] | ((unsigned)wa[3] << 16);
      lds_rec[q][jj][h ^ (jj & 7)] = rec;
    }
  }
  __syncthreads();

  const int dg = tq & 3;
  const char* vb = (const char*)(vals + ((size_t)s * N_ + n) * LQ_ * 256);
  const unsigned hd = (unsigned)((h * 32 + dg * 8) * 2);   // byte offset in row
  float facc[8] = {};
  #pragma unroll 1
  for (int l4 = 0; l4 < 4; ++l4) {
    uint4 m[4];
    #pragma unroll
    for (int p = 0; p < 4; ++p) {
      const int j = l4 * 4 + p;
      m[p] = lds_rec[q][j][h ^ (j & 7)];
    }
    f16x8 v[16];
    #pragma unroll
    for (int p = 0; p < 4; ++p) {
      v[p * 4 + 0] = *reinterpret_cast<const f16x8*>(vb + (((m[p].x & 0xffffu) << 9) + hd));
      v[p * 4 + 1] = *reinterpret_cast<const f16x8*>(vb + (((m[p].x >> 16) << 9) + hd));
      v[p * 4 + 2] = *reinterpret_cast<const f16x8*>(vb + (((m[p].y & 0xffffu) << 9) + hd));
      v[p * 4 + 3] = *reinterpret_cast<const f16x8*>(vb + (((m[p].y >> 16) << 9) + hd));
    }
    __builtin_amdgcn_sched_barrier(0);   // keep all 16 gathers in flight
    f16x2 a0 = {0, 0}, a1 = {0, 0}, a2 = {0, 0}, a3 = {0, 0};
    #pragma unroll
    for (int p = 0; p < 4; ++p) {
      const f16x2 w0 = u2h2(__builtin_amdgcn_perm(m[p].z, m[p].z, 0x01000100u));
      const f16x2 w1 = u2h2(__builtin_amdgcn_perm(m[p].z, m[p].z, 0x03020302u));
      const f16x2 w2 = u2h2(__builtin_amdgcn_perm(m[p].w, m[p].w, 0x01000100u));
      const f16x2 w3 = u2h2(__builtin_amdgcn_perm(m[p].w, m[p].w, 0x03020302u));
      const f16x2* p0 = (const f16x2*)&v[p * 4 + 0];
      const f16x2* p1 = (const f16x2*)&v[p * 4 + 1];
      const f16x2* p2 = (const f16x2*)&v[p * 4 + 2];
      const f16x2* p3 = (const f16x2*)&v[p * 4 + 3];
      a0 = __builtin_elementwise_fma(p0[0], w0, a0);
      a1 = __builtin_elementwise_fma(p0[1], w0, a1);
      a2 = __builtin_elementwise_fma(p0[2], w0, a2);
      a3 = __builtin_elementwise_fma(p0[3], w0, a3);
      a0 = __builtin_elementwise_fma(p1[0], w1, a0);
      a1 = __builtin_elementwise_fma(p1[1], w1, a1);
      a2 = __builtin_elementwise_fma(p1[2], w1, a2);
      a3 = __builtin_elementwise_fma(p1[3], w1, a3);
      a0 = __builtin_elementwise_fma(p2[0], w2, a0);
      a1 = __builtin_elementwise_fma(p2[1], w2, a1);
      a2 = __builtin_elementwise_fma(p2[2], w2, a2);
      a3 = __builtin_elementwise_fma(p2[3], w2, a3);
      a0 = __builtin_elementwise_fma(p3[0], w3, a0);
      a1 = __builtin_elementwise_fma(p3[1], w3, a1);
      a2 = __builtin_elementwise_fma(p3[2], w3, a2);
      a3 = __builtin_elementwise_fma(p3[3], w3, a3);
    }
    facc[0] += (float)a0[0]; facc[1] += (float)a0[1];
    facc[2] += (float)a1[0]; facc[3] += (float)a1[1];
    facc[4] += (float)a2[0]; facc[5] += (float)a2[1];
    facc[6] += (float)a3[0]; facc[7] += (float)a3[1];
  }
  f16x8 r;
  #pragma unroll
  for (int e2 = 0; e2 < 8; ++e2) r[e2] = (f16)facc[e2];
  *reinterpret_cast<f16x8*>(acc_out + (size_t)row * 512 + s * 256 + h * 32 + dg * 8) = r;
}

// -------------------------------- launcher -------------------------------------
extern "C" void kernel_launch(void* const* d_in, const int* in_sizes, int n_in,
                              void* d_out, int out_size, void* d_ws, size_t ws_size,
                              hipStream_t stream) {
  const float* query0 = (const float*)d_in[0];
  const float* query1 = (const float*)d_in[1];
  const float* feat0  = (const float*)d_in[2];
  const float* feat1  = (const float*)d_in[3];
  const float* refp   = (const float*)d_in[4];
  const float* W_off  = (const float*)d_in[5];
  const float* b_off  = (const float*)d_in[6];
  const float* W_attn = (const float*)d_in[7];
  const float* b_attn = (const float*)d_in[8];
  const float* W_val  = (const float*)d_in[9];
  const float* b_val  = (const float*)d_in[10];
  const float* W_out  = (const float*)d_in[11];
  const float* b_out  = (const float*)d_in[12];
  const float* W_agg  = (const float*)d_in[13];
  const float* b_agg  = (const float*)d_in[14];
  float* out = (float*)d_out;

  char* p = (char*)d_ws;
  const size_t SZ = (size_t)MQ_ * 256;                 // elems per (MQ,256)
  unsigned short* valb  = (unsigned short*)p; p += 2 * SZ * 2;
  unsigned short* oab   = (unsigned short*)p; p += (size_t)2 * MQ_ * 384 * 2;
  unsigned short* accb  = (unsigned short*)p; p += (size_t)MQ_ * 512 * 2;
  unsigned short* Wfinh = (unsigned short*)p; p += 256 * 512 * 2;
  float* bfin = (float*)p; p += 256 * 4;

  // 1) projections: val (src=0) + off/attn (src=1), both streams; weights
  //    self-converted from fp32 (no prep dependency)
  gemm_stage1<<<dim3(170, 2, 2), 256, 0, stream>>>(query0, query1, feat0, feat1,
                                                   W_val, W_off, W_attn,
                                                   b_val, b_off, b_attn,
                                                   valb, oab);
  // 2) sampling (XCD-local slabs) + fused prep tail (Wfinh, bfin)
  deform_sample<<<5440 + 513, 256, 0, stream>>>(valb, oab, refp, accb,
                                                W_agg, W_out, b_agg, b_out,
                                                Wfinh, bfin);
  // 3) final fused out+agg projection: K=512, 64-row tiles for tail balance
  gemm_final<<<dim3(340, 2), 256, 0, stream>>>(accb, Wfinh, bfin, out);
}

// Round 13
// 136.729 us; speedup vs baseline: 1.1392x; 1.1392x over previous
//
#include <hip/hip_runtime.h>
#include <math.h>

#define N_   4
#define LQ_  5440
#define MQ_  (N_*LQ_)   // 21760 rows; /8 = 2720 blocks; /128 = 170 tiles

typedef _Float16 f16;
typedef __attribute__((ext_vector_type(2))) _Float16 f16x2;
typedef __attribute__((ext_vector_type(8))) _Float16 f16x8;
typedef __attribute__((ext_vector_type(4))) float     f32x4;

__device__ __forceinline__ unsigned short f2h(float f) {
  union { f16 h; unsigned short u; } v; v.h = (f16)f; return v.u;
}
__device__ __forceinline__ float h2f(unsigned u) {   // low 16 bits
  union { unsigned short u; f16 h; } v; v.u = (unsigned short)u; return (float)v.h;
}
__device__ __forceinline__ f16x2 u2h2(unsigned u) {
  union { unsigned u; f16x2 h; } v; v.u = u; return v.h;
}

#define GLD16(gp, lp) __builtin_amdgcn_global_load_lds( \
    (const __attribute__((address_space(1))) void*)(gp), \
    (__attribute__((address_space(3))) void*)(lp), 16, 0, 0)

// -------- all weight prep in ONE dispatch (grid = 675 blocks x 256) ------------
__global__ __launch_bounds__(256)
void prep(const float* __restrict__ W_val, const float* __restrict__ W_off,
          const float* __restrict__ W_attn, const float* __restrict__ W_agg,
          const float* __restrict__ W_out, const float* __restrict__ b_off,
          const float* __restrict__ b_attn, const float* __restrict__ b_agg,
          const float* __restrict__ b_out,
          unsigned short* __restrict__ Wvalh, unsigned short* __restrict__ Wcath,
          unsigned short* __restrict__ Wfinh, float* __restrict__ bcat,
          float* __restrict__ bfin) {
  __shared__ float wrow[256];
  const int b = blockIdx.x, t = threadIdx.x;
  if (b < 160) {
    const float* src; unsigned short* dst; int i;
    if (b < 64)       { src = W_val;  dst = Wvalh;          i = b * 256 + t; }
    else if (b < 128) { src = W_off;  dst = Wcath;          i = (b - 64) * 256 + t; }
    else              { src = W_attn; dst = Wcath + 65536;  i = (b - 128) * 256 + t; }
    float4 v = reinterpret_cast<const float4*>(src)[i];
    ushort4 r;
    r.x = f2h(v.x); r.y = f2h(v.y); r.z = f2h(v.z); r.w = f2h(v.w);
    reinterpret_cast<ushort4*>(dst)[i] = r;
  } else if (b < 672) {
    const int idx = b - 160, j = idx & 255, s = idx >> 8;
    wrow[t] = W_agg[(size_t)j * 512 + s * 256 + t];
    __syncthreads();
    float a = 0.f;
    for (int i = 0; i < 256; ++i) a = fmaf(wrow[i], W_out[(size_t)i * 256 + t], a);
    Wfinh[(size_t)j * 512 + s * 256 + t] = f2h(a);
  } else if (b == 672) {
    float s = b_agg[t];
    for (int i = 0; i < 256; ++i)
      s = fmaf(W_agg[(size_t)t * 512 + i] + W_agg[(size_t)t * 512 + 256 + i], b_out[i], s);
    bfin[t] = s;
  } else if (b == 673) {
    bcat[t] = b_off[t];
  } else {
    if (t < 128) bcat[256 + t] = b_attn[t];
  }
}

// -------- stage-1 GEMM, col-tile loop INSIDE the block --------------------------
__global__ __launch_bounds__(256)
void gemm_stage1(const float* __restrict__ q0, const float* __restrict__ q1,
                 const float* __restrict__ f0, const float* __restrict__ f1,
                 const unsigned short* __restrict__ Wvalh,
                 const unsigned short* __restrict__ Wcath,
                 const float* __restrict__ b_val, const float* __restrict__ bcat,
                 unsigned short* __restrict__ valb, unsigned short* __restrict__ oab) {
  __shared__ __align__(16) unsigned short As[128 * 64];
  __shared__ __align__(16) unsigned short Ws[128 * 64];
  const int src = blockIdx.y, z = blockIdx.z;
  const size_t SZ = (size_t)MQ_ * 256;
  const float* A; const unsigned short* W; const float* bias;
  unsigned short* C; int NC, NT;
  if (src == 0) { A = z ? f1 : f0; W = Wvalh; bias = b_val; C = valb + z * SZ;               NC = 256; NT = 2; }
  else          { A = z ? q1 : q0; W = Wcath; bias = bcat;  C = oab + (size_t)z * MQ_ * 384; NC = 384; NT = 3; }

  const int t    = threadIdx.x;
  const int lane = t & 63;
  const int wv   = t >> 6;
  const int wr   = wv >> 1, wc = wv & 1;
  const int row0 = blockIdx.x * 128;
  const int srow = t >> 3, schunk = t & 7;
  const int wbase = wv * 512;

  for (int ct = 0; ct < NT; ++ct) {
    const int col0 = ct * 128;
    f32x4 acc[4][4] = {};

    for (int k0 = 0; k0 < 256; k0 += 64) {
      __syncthreads();
      #pragma unroll
      for (int i = 0; i < 4; ++i) {                // W: direct-to-LDS, pre-swizzled src
        const int row = i * 32 + srow;
        const int ch  = schunk ^ (row & 7);
        GLD16(W + (size_t)(col0 + row) * 256 + k0 + ch * 8, &Ws[i * 2048 + wbase]);
      }
      #pragma unroll
      for (int i = 0; i < 4; ++i) {                // A: fp32 reg-stage + cvt (L2-hot on ct>0)
        const int row = i * 32 + srow;
        const float* srcp = A + (size_t)(row0 + row) * 256 + k0 + schunk * 8;
        const float4 a0 = *reinterpret_cast<const float4*>(srcp);
        const float4 a1 = *reinterpret_cast<const float4*>(srcp + 4);
        f16x8 hv;
        hv[0] = (f16)a0.x; hv[1] = (f16)a0.y; hv[2] = (f16)a0.z; hv[3] = (f16)a0.w;
        hv[4] = (f16)a1.x; hv[5] = (f16)a1.y; hv[6] = (f16)a1.z; hv[7] = (f16)a1.w;
        const int ch = schunk ^ (row & 7);
        *reinterpret_cast<f16x8*>(&As[row * 64 + ch * 8]) = hv;
      }
      __syncthreads();

      f16x8 af[4][2], bfr[4][2];
      #pragma unroll
      for (int f = 0; f < 4; ++f)
        #pragma unroll
        for (int kk = 0; kk < 2; ++kk) {
          const int ra = wr * 64 + f * 16 + (lane & 15);
          const int ca = (kk * 4 + (lane >> 4)) ^ (ra & 7);
          af[f][kk] = *(const f16x8*)&As[ra * 64 + ca * 8];
          const int rb = wc * 64 + f * 16 + (lane & 15);
          const int cb = (kk * 4 + (lane >> 4)) ^ (rb & 7);
          bfr[f][kk] = *(const f16x8*)&Ws[rb * 64 + cb * 8];
        }
      #pragma unroll
      for (int kk = 0; kk < 2; ++kk)
        #pragma unroll
        for (int fm = 0; fm < 4; ++fm)
          #pragma unroll
          for (int fn = 0; fn < 4; ++fn)
            acc[fm][fn] = __builtin_amdgcn_mfma_f32_16x16x32_f16(
                af[fm][kk], bfr[fn][kk], acc[fm][fn], 0, 0, 0);
    }

    #pragma unroll
    for (int fm = 0; fm < 4; ++fm) {
      const int m = row0 + wr * 64 + fm * 16 + (lane >> 4) * 4;
      #pragma unroll
      for (int fn = 0; fn < 4; ++fn) {
        const int c = col0 + wc * 64 + fn * 16 + (lane & 15);
        const float bv = bias[c];
        #pragma unroll
        for (int r = 0; r < 4; ++r)
          C[(size_t)(m + r) * NC + c] = f2h(acc[fm][fn][r] + bv);
      }
    }
  }
}

// -------- final GEMM: out = acc(MQ,512 f16) @ Wfin^T + bfin, fp32 out ----------
// 64x128 tile (680 blocks for tail balance), K=512. 4 waves = 4 col groups.
__global__ __launch_bounds__(256)
void gemm_final(const unsigned short* __restrict__ A,
                const unsigned short* __restrict__ W,
                const float* __restrict__ bias, float* __restrict__ out) {
  __shared__ __align__(16) unsigned short As[64 * 64];    //  8 KB
  __shared__ __align__(16) unsigned short Ws[128 * 64];   // 16 KB
  const int t    = threadIdx.x;
  const int lane = t & 63;
  const int wv   = t >> 6;                 // column group 0..3 (32 cols each)
  const int row0 = blockIdx.x * 64, col0 = blockIdx.y * 128;
  const int srow = t >> 3, schunk = t & 7;
  const int wbase = wv * 512;

  f32x4 acc[4][2] = {};

  for (int k0 = 0; k0 < 512; k0 += 64) {
    __syncthreads();
    #pragma unroll
    for (int i = 0; i < 2; ++i) {          // A: 64 rows, 2 issues
      const int row = i * 32 + srow;
      const int ch  = schunk ^ (row & 7);
      GLD16(A + (size_t)(row0 + row) * 512 + k0 + ch * 8, &As[i * 2048 + wbase]);
    }
    #pragma unroll
    for (int i = 0; i < 4; ++i) {          // W: 128 rows, 4 issues
      const int row = i * 32 + srow;
      const int ch  = schunk ^ (row & 7);
      GLD16(W + (size_t)(col0 + row) * 512 + k0 + ch * 8, &Ws[i * 2048 + wbase]);
    }
    __syncthreads();

    f16x8 af[4][2], bfr[2][2];
    #pragma unroll
    for (int kk = 0; kk < 2; ++kk) {
      #pragma unroll
      for (int f = 0; f < 4; ++f) {
        const int ra = f * 16 + (lane & 15);
        const int ca = (kk * 4 + (lane >> 4)) ^ (ra & 7);
        af[f][kk] = *(const f16x8*)&As[ra * 64 + ca * 8];
      }
      #pragma unroll
      for (int fn = 0; fn < 2; ++fn) {
        const int rb = wv * 32 + fn * 16 + (lane & 15);
        const int cb = (kk * 4 + (lane >> 4)) ^ (rb & 7);
        bfr[fn][kk] = *(const f16x8*)&Ws[rb * 64 + cb * 8];
      }
    }
    #pragma unroll
    for (int kk = 0; kk < 2; ++kk)
      #pragma unroll
      for (int fm = 0; fm < 4; ++fm)
        #pragma unroll
        for (int fn = 0; fn < 2; ++fn)
          acc[fm][fn] = __builtin_amdgcn_mfma_f32_16x16x32_f16(
              af[fm][kk], bfr[fn][kk], acc[fm][fn], 0, 0, 0);
  }

  #pragma unroll
  for (int fm = 0; fm < 4; ++fm) {
    const int m = row0 + fm * 16 + (lane >> 4) * 4;
    #pragma unroll
    for (int fn = 0; fn < 2; ++fn) {
      const int c = col0 + wv * 32 + fn * 16 + (lane & 15);
      const float bv = bias[c];
      #pragma unroll
      for (int r = 0; r < 4; ++r)
        out[(size_t)(m + r) * 256 + c] = acc[fm][fn][r] + bv;
    }
  }
}

// ------------------------- deformable sampling (both streams) ------------------
// R8's proven version: grid 5440 x 256; XCD-local slabs (sn = bid & 7);
// phase 1 -> 16 KB LDS records; phase 2: per level-group issue ALL 16 f16x8
// gathers, sched_barrier(0), then consume with v_pk_fma_f16.
__global__ __launch_bounds__(256, 4)
void deform_sample(const unsigned short* __restrict__ vals,  // (2,N,LQ,256) f16
                   const unsigned short* __restrict__ oa,    // (2,MQ,384) f16
                   const float* __restrict__ refp,           // (N,LQ,4,2) f32
                   unsigned short* __restrict__ acc_out) {   // (MQ,512) f16
  const int bid = blockIdx.x;
  const int sn  = bid & 7;                // -> XCD k holds slab k
  const int s   = sn >> 2, n = sn & 3;
  const int qb  = bid >> 3;               // 0..679 within (s,n)
  const int t   = threadIdx.x;
  const int q   = t >> 5, tq = t & 31;
  const int row = n * LQ_ + qb * 8 + q;
  const int h   = tq >> 2;
  __shared__ uint4 lds_rec[8][16][8];   // 16 KB: {idx01, idx23, w01, w23}

  const unsigned short* oar = oa + ((size_t)s * MQ_ + row) * 384;
  {
    const int   l  = tq & 3;
    const int   Wn = 64 >> l;
    const float Wf = (float)Wn;
    const int   lb = (int)(((0xAD200u >> (5 * l)) & 31u) << 8);  // {0,4096,5120,5376}
    const uint4 ov = *reinterpret_cast<const uint4*>(oar + (size_t)tq * 8);
    const uint2 lv = *reinterpret_cast<const uint2*>(oar + 256 + (size_t)tq * 4);
    const float2 rxy = *reinterpret_cast<const float2*>(refp + (size_t)row * 8 + l * 2);
    float lg[4] = { h2f(lv.x), h2f(lv.x >> 16), h2f(lv.y), h2f(lv.y >> 16) };
    float mx = fmaxf(fmaxf(lg[0], lg[1]), fmaxf(lg[2], lg[3]));
    mx = fmaxf(mx, __shfl_xor(mx, 1));
    mx = fmaxf(mx, __shfl_xor(mx, 2));
    float e[4], se;
    #pragma unroll
    for (int k = 0; k < 4; ++k) e[k] = __expf(lg[k] - mx);
    se = (e[0] + e[1]) + (e[2] + e[3]);
    se += __shfl_xor(se, 1);
    se += __shfl_xor(se, 2);
    const float inv = 1.f / se;
    const unsigned od[4] = { ov.x, ov.y, ov.z, ov.w };
    #pragma unroll
    for (int k = 0; k < 4; ++k) {
      const float ox = h2f(od[k]), oy = h2f(od[k] >> 16);
      const float x = fmaf(rxy.x, Wf, ox) - 0.5f;
      const float y = fmaf(rxy.y, Wf, oy) - 0.5f;
      const float x0f = floorf(x), y0f = floorf(y);
      const int   x0 = (int)x0f,   y0 = (int)y0f;
      const float lx = x - x0f,    ly = y - y0f;
      const float aw = e[k] * inv;
      const int   xs[2] = {x0, x0 + 1}, ys[2] = {y0, y0 + 1};
      const float wx[2] = {1.f - lx, lx}, wy[2] = {1.f - ly, ly};
      unsigned ia[4]; unsigned short wa[4];
      #pragma unroll
      for (int cy = 0; cy < 2; ++cy)
        #pragma unroll
        for (int cx = 0; cx < 2; ++cx) {
          const int xi = xs[cx], yi = ys[cy];
          const bool v = (xi >= 0) && (xi < Wn) && (yi >= 0) && (yi < Wn);
          const int xc = min(max(xi, 0), Wn - 1), yc = min(max(yi, 0), Wn - 1);
          ia[cy * 2 + cx] = (unsigned)(lb + yc * Wn + xc);       // 16-bit row idx
          wa[cy * 2 + cx] = f2h(v ? wx[cx] * wy[cy] * aw : 0.f);
        }
      const int jj = l * 4 + k;
      uint4 rec;
      rec.x = ia[0] | (ia[1] << 16);
      rec.y = ia[2] | (ia[3] << 16);
      rec.z = (unsigned)wa[0] | ((unsigned)wa[1] << 16);
      rec.w = (unsigned)wa[2] | ((unsigned)wa[3] << 16);
      lds_rec[q][jj][h ^ (jj & 7)] = rec;
    }
  }
  __syncthreads();

  const int dg = tq & 3;
  const char* vb = (const char*)(vals + ((size_t)s * N_ + n) * LQ_ * 256);
  const unsigned hd = (unsigned)((h * 32 + dg * 8) * 2);   // byte offset in row
  float facc[8] = {};
  #pragma unroll 1
  for (int l4 = 0; l4 < 4; ++l4) {
    uint4 m[4];
    #pragma unroll
    for (int p = 0; p < 4; ++p) {
      const int j = l4 * 4 + p;
      m[p] = lds_rec[q][j][h ^ (j & 7)];
    }
    f16x8 v[16];
    #pragma unroll
    for (int p = 0; p < 4; ++p) {
      v[p * 4 + 0] = *reinterpret_cast<const f16x8*>(vb + (((m[p].x & 0xffffu) << 9) + hd));
      v[p * 4 + 1] = *reinterpret_cast<const f16x8*>(vb + (((m[p].x >> 16) << 9) + hd));
      v[p * 4 + 2] = *reinterpret_cast<const f16x8*>(vb + (((m[p].y & 0xffffu) << 9) + hd));
      v[p * 4 + 3] = *reinterpret_cast<const f16x8*>(vb + (((m[p].y >> 16) << 9) + hd));
    }
    __builtin_amdgcn_sched_barrier(0);   // keep all 16 gathers in flight
    f16x2 a0 = {0, 0}, a1 = {0, 0}, a2 = {0, 0}, a3 = {0, 0};
    #pragma unroll
    for (int p = 0; p < 4; ++p) {
      const f16x2 w0 = u2h2(__builtin_amdgcn_perm(m[p].z, m[p].z, 0x01000100u));
      const f16x2 w1 = u2h2(__builtin_amdgcn_perm(m[p].z, m[p].z, 0x03020302u));
      const f16x2 w2 = u2h2(__builtin_amdgcn_perm(m[p].w, m[p].w, 0x01000100u));
      const f16x2 w3 = u2h2(__builtin_amdgcn_perm(m[p].w, m[p].w, 0x03020302u));
      const f16x2* p0 = (const f16x2*)&v[p * 4 + 0];
      const f16x2* p1 = (const f16x2*)&v[p * 4 + 1];
      const f16x2* p2 = (const f16x2*)&v[p * 4 + 2];
      const f16x2* p3 = (const f16x2*)&v[p * 4 + 3];
      a0 = __builtin_elementwise_fma(p0[0], w0, a0);
      a1 = __builtin_elementwise_fma(p0[1], w0, a1);
      a2 = __builtin_elementwise_fma(p0[2], w0, a2);
      a3 = __builtin_elementwise_fma(p0[3], w0, a3);
      a0 = __builtin_elementwise_fma(p1[0], w1, a0);
      a1 = __builtin_elementwise_fma(p1[1], w1, a1);
      a2 = __builtin_elementwise_fma(p1[2], w1, a2);
      a3 = __builtin_elementwise_fma(p1[3], w1, a3);
      a0 = __builtin_elementwise_fma(p2[0], w2, a0);
      a1 = __builtin_elementwise_fma(p2[1], w2, a1);
      a2 = __builtin_elementwise_fma(p2[2], w2, a2);
      a3 = __builtin_elementwise_fma(p2[3], w2, a3);
      a0 = __builtin_elementwise_fma(p3[0], w3, a0);
      a1 = __builtin_elementwise_fma(p3[1], w3, a1);
      a2 = __builtin_elementwise_fma(p3[2], w3, a2);
      a3 = __builtin_elementwise_fma(p3[3], w3, a3);
    }
    facc[0] += (float)a0[0]; facc[1] += (float)a0[1];
    facc[2] += (float)a1[0]; facc[3] += (float)a1[1];
    facc[4] += (float)a2[0]; facc[5] += (float)a2[1];
    facc[6] += (float)a3[0]; facc[7] += (float)a3[1];
  }
  f16x8 r;
  #pragma unroll
  for (int e2 = 0; e2 < 8; ++e2) r[e2] = (f16)facc[e2];
  *reinterpret_cast<f16x8*>(acc_out + (size_t)row * 512 + s * 256 + h * 32 + dg * 8) = r;
}

// -------------------------------- launcher -------------------------------------
extern "C" void kernel_launch(void* const* d_in, const int* in_sizes, int n_in,
                              void* d_out, int out_size, void* d_ws, size_t ws_size,
                              hipStream_t stream) {
  const float* query0 = (const float*)d_in[0];
  const float* query1 = (const float*)d_in[1];
  const float* feat0  = (const float*)d_in[2];
  const float* feat1  = (const float*)d_in[3];
  const float* refp   = (const float*)d_in[4];
  const float* W_off  = (const float*)d_in[5];
  const float* b_off  = (const float*)d_in[6];
  const float* W_attn = (const float*)d_in[7];
  const float* b_attn = (const float*)d_in[8];
  const float* W_val  = (const float*)d_in[9];
  const float* b_val  = (const float*)d_in[10];
  const float* W_out  = (const float*)d_in[11];
  const float* b_out  = (const float*)d_in[12];
  const float* W_agg  = (const float*)d_in[13];
  const float* b_agg  = (const float*)d_in[14];
  float* out = (float*)d_out;

  char* p = (char*)d_ws;
  const size_t SZ = (size_t)MQ_ * 256;                 // elems per (MQ,256)
  unsigned short* valb  = (unsigned short*)p; p += 2 * SZ * 2;
  unsigned short* oab   = (unsigned short*)p; p += (size_t)2 * MQ_ * 384 * 2;
  unsigned short* accb  = (unsigned short*)p; p += (size_t)MQ_ * 512 * 2;
  unsigned short* Wvalh = (unsigned short*)p; p += 256 * 256 * 2;
  unsigned short* Wcath = (unsigned short*)p; p += 384 * 256 * 2;
  unsigned short* Wfinh = (unsigned short*)p; p += 256 * 512 * 2;
  float* bcat = (float*)p; p += 384 * 4;
  float* bfin = (float*)p; p += 256 * 4;

  prep<<<675, 256, 0, stream>>>(W_val, W_off, W_attn, W_agg, W_out, b_off, b_attn,
                                b_agg, b_out, Wvalh, Wcath, Wfinh, bcat, bfin);
  // val (src=0) + off/attn (src=1) projections, both streams, col-tiles in-block
  gemm_stage1<<<dim3(170, 2, 2), 256, 0, stream>>>(query0, query1, feat0, feat1,
                                                   Wvalh, Wcath, b_val, bcat,
                                                   valb, oab);
  // sampling, both streams, XCD-local value slabs (R8 proven version)
  deform_sample<<<5440, 256, 0, stream>>>(valb, oab, refp, accb);
  // final fused out+agg projection: K=512, 64-row tiles for tail balance
  gemm_final<<<dim3(340, 2), 256, 0, stream>>>(accb, Wfinh, bfin, out);
}